// Round 9
// baseline (869.392 us; speedup 1.0000x reference)
//
#include <hip/hip_runtime.h>
#include <hip/hip_bf16.h>
#include <hip/hip_fp16.h>

#define HEADS 4
#define DHEAD 32
#define FDIM 128   // = HEADS*DHEAD = F_IN
#define BCAP 64    // bucket capacity: deg ~ Poisson(17)+1, P(>=64) ~ 4e-19/node
#define NBLK 512   // 2 blocks/CU x 256 CUs; co-residency required for grid barrier
#define TROWS 128  // gemm tile rows (2 rows/lane)

// ---- manual grid barrier (one-shot counters, zeroed by host memset each launch) ----
// threadfence flushes this XCD's L2 (release); agent-scope acquire loads invalidate
// L1/L2 on the spinning CU so post-barrier reads see peer-XCD writes.
__device__ __forceinline__ void gridbar(int* bar, int nb) {
    __syncthreads();   // compiler emits vmcnt(0) drain before s_barrier
    if (threadIdx.x == 0) {
        __threadfence();
        __hip_atomic_fetch_add(bar, 1, __ATOMIC_ACQ_REL, __HIP_MEMORY_SCOPE_AGENT);
        while (__hip_atomic_load(bar, __ATOMIC_ACQUIRE, __HIP_MEMORY_SCOPE_AGENT) < nb)
            __builtin_amdgcn_s_sleep(8);
    }
    __syncthreads();
}

// ---- edge scatter: full-concurrency atomic binning (R5 structure) ----
__device__ __forceinline__ void scatter_phase(
    const int* __restrict__ esrc, const int* __restrict__ edst,
    int* __restrict__ deg, int* __restrict__ bucket, int e0, int e1) {
    for (int base = e0 + threadIdx.x; base < e1; base += 256 * 8) {
        int d[8], sv[8];
#pragma unroll
        for (int j = 0; j < 8; j++) {
            int idx = base + j * 256;
            d[j] = (idx < e1) ? edst[idx] : -1;
            sv[j] = (idx < e1) ? esrc[idx] : 0;
        }
#pragma unroll
        for (int j = 0; j < 8; j++) {
            if (d[j] >= 0) {
                int p = atomicAdd(&deg[d[j]], 1);
                if (p < BCAP) bucket[((size_t)d[j] << 6) + p] = sv[j];
            }
        }
    }
}

// ---- gemm: wave w = head w (W reads wave-uniform -> LDS broadcast, no conflicts);
// lane l owns rows 2l,2l+1 of a 128-row tile; grid-stride over tiles. ----
__device__ void gemm_phase(
    const float* __restrict__ X, const float* __restrict__ W,
    const float* __restrict__ al, const float* __restrict__ ar,
    __half* __restrict__ feat, float* __restrict__ el, float* __restrict__ er,
    int n, float* Wl, int tile0, int tstride) {
    {
        const float4* W4 = (const float4*)W;
        float4* Wl4 = (float4*)Wl;
        for (int i = threadIdx.x; i < FDIM * FDIM / 4; i += 256) Wl4[i] = W4[i];
    }
    __syncthreads();

    int h = __builtin_amdgcn_readfirstlane(threadIdx.x >> 6);
    int lane = threadIdx.x & 63;
    const float* wbase = Wl + h * DHEAD;
    int ntiles = (n + TROWS - 1) / TROWS;

    for (int t = tile0; t < ntiles; t += tstride) {
        int rb = t * TROWS + lane * 2;
        bool v0 = rb < n, v1 = rb + 1 < n;
        const float4* x0 = (const float4*)(X + (size_t)(v0 ? rb : n - 1) * FDIM);
        const float4* x1 = (const float4*)(X + (size_t)(v1 ? rb + 1 : n - 1) * FDIM);

        float acc0[32], acc1[32];
#pragma unroll
        for (int j = 0; j < 32; j++) { acc0[j] = 0.f; acc1[j] = 0.f; }

        for (int k4 = 0; k4 < FDIM / 4; k4++) {
            float4 a0 = x0[k4], a1 = x1[k4];
#pragma unroll
            for (int kk = 0; kk < 4; kk++) {
                const float4* wr = (const float4*)(wbase + (k4 * 4 + kk) * FDIM);
                float s0 = (&a0.x)[kk], s1 = (&a1.x)[kk];
#pragma unroll
                for (int j4 = 0; j4 < 8; j4++) {
                    float4 wv = wr[j4];
                    acc0[j4*4+0] += s0 * wv.x; acc1[j4*4+0] += s1 * wv.x;
                    acc0[j4*4+1] += s0 * wv.y; acc1[j4*4+1] += s1 * wv.y;
                    acc0[j4*4+2] += s0 * wv.z; acc1[j4*4+2] += s1 * wv.z;
                    acc0[j4*4+3] += s0 * wv.w; acc1[j4*4+3] += s1 * wv.w;
                }
            }
        }

        float el0 = 0.f, er0 = 0.f, el1 = 0.f, er1 = 0.f;
#pragma unroll
        for (int j = 0; j < 32; j++) {
            float va = al[h * DHEAD + j], vr = ar[h * DHEAD + j];
            el0 += acc0[j] * va; er0 += acc0[j] * vr;
            el1 += acc1[j] * va; er1 += acc1[j] * vr;
        }
        if (v0) { el[(size_t)rb * HEADS + h] = el0; er[(size_t)rb * HEADS + h] = er0; }
        if (v1) { el[(size_t)(rb+1) * HEADS + h] = el1; er[(size_t)(rb+1) * HEADS + h] = er1; }

        if (v0) {
            union { __half2 h2[16]; uint4 u4[4]; } pk;
#pragma unroll
            for (int m = 0; m < 16; m++) pk.h2[m] = __floats2half2_rn(acc0[2*m], acc0[2*m+1]);
            uint4* dp = (uint4*)(feat + (size_t)rb * FDIM + h * DHEAD);
#pragma unroll
            for (int q = 0; q < 4; q++) dp[q] = pk.u4[q];
        }
        if (v1) {
            union { __half2 h2[16]; uint4 u4[4]; } pk;
#pragma unroll
            for (int m = 0; m < 16; m++) pk.h2[m] = __floats2half2_rn(acc1[2*m], acc1[2*m+1]);
            uint4* dp = (uint4*)(feat + (size_t)(rb+1) * FDIM + h * DHEAD);
#pragma unroll
            for (int q = 0; q < 4; q++) dp[q] = pk.u4[q];
        }
    }
}

// ---- aggregation: one wave per node, grid-stride; lane l owns feats 2l,2l+1.
// Max-subtraction elided: scores bounded ~[-1,4]. 8-deep MLP batching. ----
__device__ void agg_phase(
    const int* __restrict__ bucket, const int* __restrict__ deg,
    const __half2* __restrict__ feat2h, const float* __restrict__ el,
    const float* __restrict__ er, const float* __restrict__ b,
    float* __restrict__ out, int n, int apply_act) {
    int wave = threadIdx.x >> 6;
    int lane = threadIdx.x & 63;
    int h = lane >> 4;
    float2 bv = ((const float2*)b)[lane];
    int stride = gridDim.x * 4;

    for (int node = blockIdx.x * 4 + wave; node < n; node += stride) {
        int nd = __builtin_amdgcn_readfirstlane(node);
        float ern = er[(size_t)nd * HEADS + h];
        int cnt = __builtin_amdgcn_readfirstlane(deg[nd]);
        const int* bkt = bucket + ((size_t)nd << 6);

        float ax = 0.f, ay = 0.f, sw = 0.f;
        int i = 0;
        for (; i + 8 <= cnt; i += 8) {
            int s[8];
#pragma unroll
            for (int j = 0; j < 8; j++) s[j] = bkt[i + j];
            float e[8];
#pragma unroll
            for (int j = 0; j < 8; j++) e[j] = el[(size_t)s[j] * HEADS + h];
            __half2 f[8];
#pragma unroll
            for (int j = 0; j < 8; j++) f[j] = feat2h[(size_t)s[j] * 64 + lane];
#pragma unroll
            for (int j = 0; j < 8; j++) {
                float ev = e[j] + ern;
                ev = ev > 0.f ? ev : 0.2f * ev;
                float w = __expf(ev);
                float2 fv = __half22float2(f[j]);
                sw += w; ax += w * fv.x; ay += w * fv.y;
            }
        }
        for (; i + 2 <= cnt; i += 2) {
            int s0 = bkt[i], s1 = bkt[i + 1];
            float e0 = el[(size_t)s0 * HEADS + h];
            float e1 = el[(size_t)s1 * HEADS + h];
            __half2 f0 = feat2h[(size_t)s0 * 64 + lane];
            __half2 f1 = feat2h[(size_t)s1 * 64 + lane];
            e0 += ern; e0 = e0 > 0.f ? e0 : 0.2f * e0;
            e1 += ern; e1 = e1 > 0.f ? e1 : 0.2f * e1;
            float w0 = __expf(e0), w1 = __expf(e1);
            float2 fv0 = __half22float2(f0), fv1 = __half22float2(f1);
            sw += w0 + w1;
            ax += w0 * fv0.x + w1 * fv1.x;
            ay += w0 * fv0.y + w1 * fv1.y;
        }
        if (i < cnt) {
            int s0 = bkt[i];
            float e0 = el[(size_t)s0 * HEADS + h] + ern;
            e0 = e0 > 0.f ? e0 : 0.2f * e0;
            float w0 = __expf(e0);
            float2 fv0 = __half22float2(feat2h[(size_t)s0 * 64 + lane]);
            sw += w0; ax += w0 * fv0.x; ay += w0 * fv0.y;
        }

        float inv = 1.0f / sw;
        float ox = ax * inv + bv.x;
        float oy = ay * inv + bv.y;
        if (apply_act) {
            ox = ox > 0.f ? ox : 0.01f * ox;
            oy = oy > 0.f ? oy : 0.01f * oy;
        }
        float2 o; o.x = ox; o.y = oy;
        ((float2*)out)[(size_t)nd * 64 + lane] = o;
    }
}

// ---- single persistent kernel: [scatter || gemm1] -> agg1 -> gemm2 -> agg2 ----
__global__ __launch_bounds__(256, 2) void k_fused(
    const float* __restrict__ x, const int* __restrict__ src, const int* __restrict__ dst,
    const float* __restrict__ W1, const float* __restrict__ al1, const float* __restrict__ ar1,
    const float* __restrict__ b1, const float* __restrict__ W2, const float* __restrict__ al2,
    const float* __restrict__ ar2, const float* __restrict__ b2,
    __half* __restrict__ feat, float* __restrict__ elb, float* __restrict__ erb,
    int* __restrict__ bar, int* __restrict__ deg, int* __restrict__ bucket,
    float* __restrict__ out, int N, int E) {
    __shared__ float Wl[FDIM * FDIM];   // 64 KB -> exactly 2 blocks/CU

    // phase 0: even blocks scatter (524K chains = R5 concurrency),
    //          odd blocks gemm1 -> true pipe overlap (atomics vs VALU)
    if ((blockIdx.x & 1) == 0) {
        int eb = blockIdx.x >> 1;                 // 0..255
        int e0 = (int)((long long)E * eb / (NBLK / 2));
        int e1 = (int)((long long)E * (eb + 1) / (NBLK / 2));
        scatter_phase(src, dst, deg, bucket, e0, e1);
    } else {
        gemm_phase(x, W1, al1, ar1, feat, elb, erb, N, Wl, blockIdx.x >> 1, NBLK / 2);
    }
    gridbar(bar + 0, gridDim.x);

    // phase 1: layer-1 aggregation (leaky 0.01) -> out used as h buffer
    agg_phase(bucket, deg, (const __half2*)feat, elb, erb, b1, out, N, 1);
    gridbar(bar + 16, gridDim.x);

    // phase 2: gemm2 on h (all blocks)
    gemm_phase(out, W2, al2, ar2, feat, elb, erb, N, Wl, blockIdx.x, NBLK);
    gridbar(bar + 32, gridDim.x);

    // phase 3: layer-2 aggregation (no activation) -> final out
    agg_phase(bucket, deg, (const __half2*)feat, elb, erb, b2, out, N, 0);
}

// ---------------- launch ----------------

extern "C" void kernel_launch(void* const* d_in, const int* in_sizes, int n_in,
                              void* d_out, int out_size, void* d_ws, size_t ws_size,
                              hipStream_t stream) {
    const float* x   = (const float*)d_in[0];
    const int*   src = (const int*)d_in[1];
    const int*   dst = (const int*)d_in[2];
    const float* W1  = (const float*)d_in[3];
    const float* al1 = (const float*)d_in[4];
    const float* ar1 = (const float*)d_in[5];
    const float* b1  = (const float*)d_in[6];
    const float* W2  = (const float*)d_in[7];
    const float* al2 = (const float*)d_in[8];
    const float* ar2 = (const float*)d_in[9];
    const float* b2  = (const float*)d_in[10];
    int N = in_sizes[0] / FDIM;
    int E = in_sizes[1];
    float* out = (float*)d_out;

    // workspace layout (~26 MB)
    __half* featA = (__half*)d_ws;                       // N*128 halves
    float*  elb   = (float*)(featA + (size_t)N * FDIM);  // N*4
    float*  erb   = elb + (size_t)N * HEADS;             // N*4
    int*    bar   = (int*)(erb + (size_t)N * HEADS);     // 48 (3 barrier slots, 64B apart)
    int*    deg   = bar + 48;                            // N
    int*    bucket= deg + N;                             // N*64

    // zero barrier counters + deg in one memset
    hipMemsetAsync(bar, 0, (size_t)(48 + N) * sizeof(int), stream);

    k_fused<<<NBLK, 256, 0, stream>>>(x, src, dst, W1, al1, ar1, b1, W2, al2, ar2, b2,
                                      featA, elb, erb, bar, deg, bucket, out, N, E);
}

// Round 10
// 301.620 us; speedup vs baseline: 2.8824x; 2.8824x over previous
//
#include <hip/hip_runtime.h>
#include <hip/hip_bf16.h>
#include <hip/hip_fp16.h>

#define HEADS 4
#define DHEAD 32
#define FDIM 128   // = HEADS*DHEAD = F_IN
#define BCAP 64    // bucket capacity: deg ~ Poisson(17)+1, P(>=64) ~ 4e-19/node
#define EPT 24     // edge slots/thread in gemm1 (196 blocks -> ~17 used)

// ---------------- GEMM + el/er + issue-ahead edge scatter ----------------
// GEMM: wave w owns head w (W reads wave-uniform -> LDS broadcast, conflict-free);
// lane l register-blocks rows 4l..4l+3; block = 256 rows x 4 heads.
// Scatter (layer 1, E>0): all ~850K atomicAdds are issued BEFORE the K-loop and
// complete on the fabric while the VALU runs the 16K-FMA loop (R7 showed
// sequential phases are additive: 87 us = 55 + 27; this overlaps them).
// Bucket stores (need atomic results) go after the K-loop.
__global__ __launch_bounds__(256) void k_gemm(
    const float* __restrict__ X, const float* __restrict__ W,
    const float* __restrict__ al, const float* __restrict__ ar,
    __half* __restrict__ feat, float* __restrict__ el, float* __restrict__ er, int n,
    const int* __restrict__ esrc, const int* __restrict__ edst,
    int* __restrict__ deg, int* __restrict__ bucket, int E) {
    __shared__ float Wl[FDIM * FDIM];   // 64 KB
    {
        const float4* W4 = (const float4*)W;
        float4* Wl4 = (float4*)Wl;
        for (int i = threadIdx.x; i < FDIM * FDIM / 4; i += 256) Wl4[i] = W4[i];
    }

    // ---- edge loads + atomic issue (independent of LDS staging) ----
    int d[EPT], sv[EPT], p[EPT];
    int e0 = 0, e1 = 0;
    if (E > 0) {
        e0 = (int)((long long)E * blockIdx.x / gridDim.x);
        e1 = (int)((long long)E * (blockIdx.x + 1) / gridDim.x);
#pragma unroll
        for (int j = 0; j < EPT; j++) {
            int idx = e0 + threadIdx.x + j * 256;
            bool ok = idx < e1;
            d[j] = ok ? edst[idx] : -1;
            sv[j] = ok ? esrc[idx] : 0;
        }
#pragma unroll
        for (int j = 0; j < EPT; j++)
            if (d[j] >= 0) p[j] = atomicAdd(&deg[d[j]], 1);
    }
    __syncthreads();

    int h = __builtin_amdgcn_readfirstlane(threadIdx.x >> 6);  // wave-uniform head
    int lane = threadIdx.x & 63;
    int rb = blockIdx.x * 256 + lane * 4;

    bool v[4];
    const float4* xp[4];
#pragma unroll
    for (int i = 0; i < 4; i++) {
        v[i] = (rb + i) < n;
        int cr = v[i] ? (rb + i) : (n - 1);
        xp[i] = (const float4*)(X + (size_t)cr * FDIM);
    }

    float acc[4][32];
#pragma unroll
    for (int i = 0; i < 4; i++)
#pragma unroll
        for (int j = 0; j < 32; j++) acc[i][j] = 0.f;

    const float* wbase = Wl + h * DHEAD;

    for (int k4 = 0; k4 < FDIM / 4; k4++) {
        float4 a[4];
#pragma unroll
        for (int i = 0; i < 4; i++) a[i] = xp[i][k4];
#pragma unroll
        for (int kk = 0; kk < 4; kk++) {
            const float4* wr = (const float4*)(wbase + (k4 * 4 + kk) * FDIM);
            float s[4];
#pragma unroll
            for (int i = 0; i < 4; i++) s[i] = (&a[i].x)[kk];
#pragma unroll
            for (int j4 = 0; j4 < 8; j4++) {
                float4 wv = wr[j4];            // uniform addr -> LDS broadcast
#pragma unroll
                for (int i = 0; i < 4; i++) {
                    acc[i][j4*4+0] += s[i] * wv.x;
                    acc[i][j4*4+1] += s[i] * wv.y;
                    acc[i][j4*4+2] += s[i] * wv.z;
                    acc[i][j4*4+3] += s[i] * wv.w;
                }
            }
        }
    }

    // ---- bucket stores (atomic results returned during the K-loop) ----
    if (E > 0) {
#pragma unroll
        for (int j = 0; j < EPT; j++)
            if (d[j] >= 0 && p[j] < BCAP) bucket[((size_t)d[j] << 6) + p[j]] = sv[j];
        // fallback for chunks larger than EPT*256 (not hit at E=850K, grid 196)
        for (int idx = e0 + threadIdx.x + EPT * 256; idx < e1; idx += 256) {
            int dd = edst[idx];
            int pp = atomicAdd(&deg[dd], 1);
            if (pp < BCAP) bucket[((size_t)dd << 6) + pp] = esrc[idx];
        }
    }

    // el/er dot products (al/ar reads wave-uniform)
    float elv[4], erv[4];
#pragma unroll
    for (int i = 0; i < 4; i++) { elv[i] = 0.f; erv[i] = 0.f; }
#pragma unroll
    for (int j = 0; j < 32; j++) {
        float va = al[h * DHEAD + j], vr = ar[h * DHEAD + j];
#pragma unroll
        for (int i = 0; i < 4; i++) {
            elv[i] += acc[i][j] * va;
            erv[i] += acc[i][j] * vr;
        }
    }
#pragma unroll
    for (int i = 0; i < 4; i++) {
        if (v[i]) {
            el[(size_t)(rb + i) * HEADS + h] = elv[i];
            er[(size_t)(rb + i) * HEADS + h] = erv[i];
        }
    }

    // feat store: fp16, 4x uint4 per row slice
#pragma unroll
    for (int i = 0; i < 4; i++) {
        if (!v[i]) continue;
        union { __half2 h2[16]; uint4 u4[4]; } pk;
#pragma unroll
        for (int m = 0; m < 16; m++)
            pk.h2[m] = __floats2half2_rn(acc[i][2*m], acc[i][2*m+1]);
        uint4* dstp = (uint4*)(feat + (size_t)(rb + i) * FDIM + h * DHEAD);
#pragma unroll
        for (int t = 0; t < 4; t++) dstp[t] = pk.u4[t];
    }
}

// ---------------- per-node softmax aggregation ----------------
// One wave per dst node; lane l owns features 2l,2l+1 (head = l>>4).
// feat gathered as __half2 (4 B/lane = 256 B/edge). Unroll 8 for MLP.
// Max-subtraction elided: scores bounded ~[-1,4], exp well-conditioned.
__global__ __launch_bounds__(256) void k_aggregate(
    const int* __restrict__ bucket, const int* __restrict__ deg,
    const __half2* __restrict__ feat2h, const float* __restrict__ el,
    const float* __restrict__ er, const float* __restrict__ b,
    float* __restrict__ out, int n, int apply_act) {
    int wave = threadIdx.x >> 6;
    int node = blockIdx.x * 4 + wave;
    if (node >= n) return;
    node = __builtin_amdgcn_readfirstlane(node);
    int lane = threadIdx.x & 63;
    int h = lane >> 4;

    float ern = er[(size_t)node * HEADS + h];
    int cnt = __builtin_amdgcn_readfirstlane(deg[node]);
    const int* bkt = bucket + ((size_t)node << 6);

    float ax = 0.f, ay = 0.f, sw = 0.f;
    int i = 0;

    for (; i + 8 <= cnt; i += 8) {
        int s[8];
#pragma unroll
        for (int j = 0; j < 8; j++) s[j] = bkt[i + j];
        float e[8];
#pragma unroll
        for (int j = 0; j < 8; j++) e[j] = el[(size_t)s[j] * HEADS + h];
        __half2 f[8];
#pragma unroll
        for (int j = 0; j < 8; j++) f[j] = feat2h[(size_t)s[j] * 64 + lane];
#pragma unroll
        for (int j = 0; j < 8; j++) {
            float ev = e[j] + ern;
            ev = ev > 0.f ? ev : 0.2f * ev;
            float w = __expf(ev);
            float2 fv = __half22float2(f[j]);
            sw += w; ax += w * fv.x; ay += w * fv.y;
        }
    }
    for (; i + 2 <= cnt; i += 2) {
        int s0 = bkt[i], s1 = bkt[i + 1];
        float e0 = el[(size_t)s0 * HEADS + h];
        float e1 = el[(size_t)s1 * HEADS + h];
        __half2 f0 = feat2h[(size_t)s0 * 64 + lane];
        __half2 f1 = feat2h[(size_t)s1 * 64 + lane];
        e0 += ern; e0 = e0 > 0.f ? e0 : 0.2f * e0;
        e1 += ern; e1 = e1 > 0.f ? e1 : 0.2f * e1;
        float w0 = __expf(e0), w1 = __expf(e1);
        float2 fv0 = __half22float2(f0), fv1 = __half22float2(f1);
        sw += w0 + w1;
        ax += w0 * fv0.x + w1 * fv1.x;
        ay += w0 * fv0.y + w1 * fv1.y;
    }
    if (i < cnt) {
        int s0 = bkt[i];
        float e0 = el[(size_t)s0 * HEADS + h] + ern;
        e0 = e0 > 0.f ? e0 : 0.2f * e0;
        float w0 = __expf(e0);
        float2 fv0 = __half22float2(feat2h[(size_t)s0 * 64 + lane]);
        sw += w0; ax += w0 * fv0.x; ay += w0 * fv0.y;
    }

    float inv = 1.0f / sw;
    float2 bv = ((const float2*)b)[lane];
    float ox = ax * inv + bv.x;
    float oy = ay * inv + bv.y;
    if (apply_act) {
        ox = ox > 0.f ? ox : 0.01f * ox;
        oy = oy > 0.f ? oy : 0.01f * oy;
    }
    float2 o; o.x = ox; o.y = oy;
    ((float2*)out)[(size_t)node * 64 + lane] = o;
}

// ---------------- launch ----------------

extern "C" void kernel_launch(void* const* d_in, const int* in_sizes, int n_in,
                              void* d_out, int out_size, void* d_ws, size_t ws_size,
                              hipStream_t stream) {
    const float* x   = (const float*)d_in[0];
    const int*   src = (const int*)d_in[1];
    const int*   dst = (const int*)d_in[2];
    const float* W1  = (const float*)d_in[3];
    const float* al1 = (const float*)d_in[4];
    const float* ar1 = (const float*)d_in[5];
    const float* b1  = (const float*)d_in[6];
    const float* W2  = (const float*)d_in[7];
    const float* al2 = (const float*)d_in[8];
    const float* ar2 = (const float*)d_in[9];
    const float* b2  = (const float*)d_in[10];
    int N = in_sizes[0] / FDIM;
    int E = in_sizes[1];
    float* out = (float*)d_out;

    // workspace layout
    __half* featA = (__half*)d_ws;                      // N*128 halves (12.8 MB)
    float* elb    = (float*)(featA + (size_t)N * FDIM); // N*4 fp32
    float* erb    = elb + (size_t)N * HEADS;            // N*4
    int*   deg    = (int*)(erb + (size_t)N * HEADS);    // N
    int*   bucket = deg + N;                            // N*64 ints
    float* hbuf   = out;   // reuse d_out as layer-1 output (overwritten by layer 2)

    int gblocks = (N + 255) / 256;

    // deg must be zero before the fused scatter
    hipMemsetAsync(deg, 0, (size_t)N * sizeof(int), stream);

    // layer 1 (gemm + issue-ahead edge scatter)
    k_gemm<<<gblocks, 256, 0, stream>>>(x, W1, al1, ar1, featA, elb, erb, N,
                                        src, dst, deg, bucket, E);
    k_aggregate<<<(N + 3) / 4, 256, 0, stream>>>(bucket, deg, (const __half2*)featA,
                                                 elb, erb, b1, hbuf, N, 1);

    // layer 2 (pure gemm: E=0)
    k_gemm<<<gblocks, 256, 0, stream>>>(hbuf, W2, al2, ar2, featA, elb, erb, N,
                                        nullptr, nullptr, nullptr, nullptr, 0);
    k_aggregate<<<(N + 3) / 4, 256, 0, stream>>>(bucket, deg, (const __half2*)featA,
                                                 elb, erb, b2, out, N, 0);
}